// Round 1
// baseline (1142.529 us; speedup 1.0000x reference)
//
#include <hip/hip_runtime.h>

// Direct 3x3 conv, NCHW fp32. x:(16,64,224,224) W:(64,64,3,3) b:(64) -> out:(16,64,224,224)
// Block: 256 threads = 8 (w-groups) x 32 (h). Tile: 32x32 spatial, 16 output channels.
// Each thread: 4 consecutive w-pixels x 16 k accumulators.
// Weights read as wave-uniform scalar loads (SMEM path); input tile staged in LDS.

#define TW 32
#define TH 32
#define KB 16
#define PXT 4

__global__ __launch_bounds__(256) void conv3x3_direct(
    const float* __restrict__ x, const float* __restrict__ wgt,
    const float* __restrict__ bias, float* __restrict__ out) {
  __shared__ float xs[34 * 35];  // 34 rows, stride 35 (odd) to spread banks

  const int tx = blockIdx.x % 7;   // w-tile index
  const int ty = blockIdx.x / 7;   // h-tile index
  const int k0 = blockIdx.y * KB;
  const int n  = blockIdx.z;
  const int w0 = tx * TW, h0 = ty * TH;
  const int tid = threadIdx.x;
  const int tw = tid & 7;    // 0..7  -> pixels w0 + 4*tw .. +3
  const int th = tid >> 3;   // 0..31 -> row h0 + th

  float acc[KB][PXT];
#pragma unroll
  for (int k = 0; k < KB; ++k)
#pragma unroll
    for (int p = 0; p < PXT; ++p) acc[k][p] = 0.f;

  const float* xn = x + (size_t)n * 64 * 224 * 224;

  for (int c = 0; c < 64; ++c) {
    const float* xc = xn + (size_t)c * 224 * 224;

    // ---- stage 34x34 halo tile into LDS (zero-pad out of bounds) ----
    for (int i = tid; i < 34 * 34; i += 256) {
      int row = i / 34;
      int col = i - row * 34;
      int gh = h0 - 1 + row;
      int gw = w0 - 1 + col;
      float v = 0.f;
      if (gh >= 0 && gh < 224 && gw >= 0 && gw < 224) v = xc[gh * 224 + gw];
      xs[row * 35 + col] = v;
    }
    __syncthreads();

    // ---- per-thread input window: 3 rows x 6 cols (covers 4 pixels x 3 taps) ----
    float in[3][6];
#pragma unroll
    for (int r = 0; r < 3; ++r)
#pragma unroll
      for (int q = 0; q < 6; ++q)
        in[r][q] = xs[(th + r) * 35 + tw * PXT + q];

    const float* wc = wgt + ((size_t)k0 * 64 + c) * 9;
#pragma unroll
    for (int k = 0; k < KB; ++k) {
      const float* wk = wc + (size_t)k * 64 * 9;  // W[k0+k][c][0][0]
#pragma unroll
      for (int r = 0; r < 3; ++r)
#pragma unroll
        for (int s = 0; s < 3; ++s) {
          float wv = wk[r * 3 + s];  // block-uniform -> scalar load
#pragma unroll
          for (int p = 0; p < PXT; ++p) acc[k][p] += wv * in[r][s + p];
        }
    }
    __syncthreads();
  }

  // ---- epilogue: add bias, coalesced float4 stores ----
#pragma unroll
  for (int k = 0; k < KB; ++k) {
    float bv = bias[k0 + k];
    float4 v = make_float4(acc[k][0] + bv, acc[k][1] + bv,
                           acc[k][2] + bv, acc[k][3] + bv);
    float* op = out + ((((size_t)n * 64 + (k0 + k)) * 224 + (h0 + th)) * 224
                       + (w0 + tw * PXT));
    *reinterpret_cast<float4*>(op) = v;
  }
}

extern "C" void kernel_launch(void* const* d_in, const int* in_sizes, int n_in,
                              void* d_out, int out_size, void* d_ws, size_t ws_size,
                              hipStream_t stream) {
  const float* x = (const float*)d_in[0];
  const float* W = (const float*)d_in[1];
  const float* b = (const float*)d_in[2];
  float* out = (float*)d_out;

  dim3 grid(7 * 7, 64 / KB, 16);  // 49 tiles, 4 k-groups, 16 images
  dim3 block(256);
  conv3x3_direct<<<grid, block, 0, stream>>>(x, W, b, out);
}

// Round 2
// 470.105 us; speedup vs baseline: 2.4304x; 2.4304x over previous
//
#include <hip/hip_runtime.h>
#include <hip/hip_bf16.h>

// bf16 implicit-GEMM 3x3 conv for x:(16,64,224,224) f32, W:(64,64,3,3) f32, b:(64).
// 9 tap-shifted GEMMs (M=pixels, N=64 kout, K=64 c) on v_mfma_f32_32x32x16_bf16.
// Block: 256 thr (4 waves). Tile: 16 rows x 32 cols x all 64 kout.
// Wave: 4 rows (M=128) -> acc 4 rb x 2 nb x float16 = 128 VGPRs.
// LDS: x-tile [h][c/8][w][c%8] bf16, 18x8x34x8 = 78336 B -> 2 blocks/CU.
// Weights pre-transposed to Wt[tap][kout][c] bf16 in d_ws (73.7 KB, L2-hot);
// B-frags read from global (no LDS, no extra barrier).

typedef __attribute__((ext_vector_type(8)))  short   short8;
typedef __attribute__((ext_vector_type(8)))  unsigned short ushort8;
typedef __attribute__((ext_vector_type(16))) float   float16_t;

#define HW (224 * 224)

__device__ __forceinline__ unsigned short f2bf(float f) {
  __hip_bfloat16 h = __float2bfloat16(f);  // RNE
  return *reinterpret_cast<unsigned short*>(&h);
}

// ---- pre-kernel: Wt[tap][kout][c] bf16 <- W[kout][c][tap] fp32 ----
__global__ void build_wt(const float* __restrict__ W, unsigned short* __restrict__ wt) {
  int i = blockIdx.x * 256 + threadIdx.x;  // 0 .. 36863
  if (i < 9 * 64 * 64) {
    int tap = i >> 12;          // /4096
    int rem = i & 4095;
    int nn  = rem >> 6;
    int c   = rem & 63;
    wt[i] = f2bf(W[(nn * 64 + c) * 9 + tap]);
  }
}

// ---- main kernel ----
__global__ __launch_bounds__(256, 2) void conv3x3_mfma(
    const float* __restrict__ x, const unsigned short* __restrict__ wt,
    const float* __restrict__ bias, float* __restrict__ out) {
  __shared__ __align__(16) unsigned short xs[18 * 8 * 34 * 8];  // [h][cg][w][c8]

  const int w0  = blockIdx.x * 32;
  const int h0  = blockIdx.y * 16;
  const int img = blockIdx.z;
  const int tid = threadIdx.x;
  const int lane = tid & 63, wave = tid >> 6;
  const int ln31 = lane & 31, lhi = lane >> 5;

  const float* xn = x + (size_t)img * 64 * HW;

  // ---- stage 18x34 halo tile, transposing to c-innermost bf16 ----
  for (int i = tid; i < 18 * 8 * 34; i += 256) {
    int h   = i / (8 * 34);
    int rem = i - h * (8 * 34);
    int cg  = rem / 34;
    int w   = rem - cg * 34;
    int gh = h0 - 1 + h;
    int gw = w0 - 1 + w;
    ushort8 pk;
    if ((unsigned)gh < 224u && (unsigned)gw < 224u) {
      const float* p = xn + (size_t)cg * 8 * HW + gh * 224 + gw;
#pragma unroll
      for (int j = 0; j < 8; ++j) pk[j] = f2bf(p[(size_t)j * HW]);
    } else {
#pragma unroll
      for (int j = 0; j < 8; ++j) pk[j] = 0;
    }
    *reinterpret_cast<ushort8*>(&xs[i * 8]) = pk;
  }
  __syncthreads();

  // ---- MFMA main loop: 9 taps x 4 ksteps x 4 row-blocks x 2 n-blocks ----
  const int row0 = wave * 4;
  float16_t acc[4][2];
#pragma unroll
  for (int rb = 0; rb < 4; ++rb)
#pragma unroll
    for (int nb = 0; nb < 2; ++nb) acc[rb][nb] = 0.f;

#pragma unroll
  for (int r = 0; r < 3; ++r) {
#pragma unroll
    for (int s = 0; s < 3; ++s) {
      const int tap = r * 3 + s;
      // B-frags for this tap: B[k=c][n=kout], lane: n=ln31, k=lhi*8+j
      short8 bq[4][2];
#pragma unroll
      for (int ks = 0; ks < 4; ++ks)
#pragma unroll
        for (int nb = 0; nb < 2; ++nb)
          bq[ks][nb] = *reinterpret_cast<const short8*>(
              wt + ((tap * 64 + nb * 32 + ln31) * 64 + ks * 16 + lhi * 8));

#pragma unroll
      for (int ks = 0; ks < 4; ++ks) {
        const int cg = ks * 2 + lhi;
#pragma unroll
        for (int rb = 0; rb < 4; ++rb) {
          const int hidx = row0 + rb + r;
          const int widx = ln31 + s;
          const short8 a = *reinterpret_cast<const short8*>(
              &xs[(((hidx * 8) + cg) * 34 + widx) * 8]);
          acc[rb][0] = __builtin_amdgcn_mfma_f32_32x32x16_bf16(a, bq[ks][0], acc[rb][0], 0, 0, 0);
          acc[rb][1] = __builtin_amdgcn_mfma_f32_32x32x16_bf16(a, bq[ks][1], acc[rb][1], 0, 0, 0);
        }
      }
    }
  }

  // ---- epilogue: D lane mapping m=(reg&3)+8*(reg>>2)+4*lhi, n=ln31 ----
#pragma unroll
  for (int rb = 0; rb < 4; ++rb) {
    const int h = h0 + row0 + rb;
#pragma unroll
    for (int nb = 0; nb < 2; ++nb) {
      const int ch = nb * 32 + ln31;
      const float bv = bias[ch];
      float* op = out + (((size_t)img * 64 + ch) * 224 + h) * 224 + w0;
#pragma unroll
      for (int q = 0; q < 4; ++q) {
        const int wloc = 8 * q + 4 * lhi;
        float4 v;
        v.x = acc[rb][nb][4 * q + 0] + bv;
        v.y = acc[rb][nb][4 * q + 1] + bv;
        v.z = acc[rb][nb][4 * q + 2] + bv;
        v.w = acc[rb][nb][4 * q + 3] + bv;
        *reinterpret_cast<float4*>(op + wloc) = v;
      }
    }
  }
}

// ---- fallback (round-1 direct fp32) if d_ws is too small for Wt ----
#define TW 32
#define TH 32
#define KB 16
#define PXT 4
__global__ __launch_bounds__(256) void conv3x3_direct(
    const float* __restrict__ x, const float* __restrict__ wgt,
    const float* __restrict__ bias, float* __restrict__ out) {
  __shared__ float xsf[34 * 35];
  const int tx = blockIdx.x % 7, ty = blockIdx.x / 7;
  const int k0 = blockIdx.y * KB, n = blockIdx.z;
  const int w0 = tx * TW, h0 = ty * TH;
  const int tid = threadIdx.x;
  const int tw = tid & 7, th = tid >> 3;
  float acc[KB][PXT];
#pragma unroll
  for (int k = 0; k < KB; ++k)
#pragma unroll
    for (int p = 0; p < PXT; ++p) acc[k][p] = 0.f;
  const float* xn = x + (size_t)n * 64 * HW;
  for (int c = 0; c < 64; ++c) {
    const float* xc = xn + (size_t)c * HW;
    for (int i = tid; i < 34 * 34; i += 256) {
      int row = i / 34, col = i - row * 34;
      int gh = h0 - 1 + row, gw = w0 - 1 + col;
      float v = 0.f;
      if (gh >= 0 && gh < 224 && gw >= 0 && gw < 224) v = xc[gh * 224 + gw];
      xsf[row * 35 + col] = v;
    }
    __syncthreads();
    float in[3][6];
#pragma unroll
    for (int r = 0; r < 3; ++r)
#pragma unroll
      for (int q = 0; q < 6; ++q) in[r][q] = xsf[(th + r) * 35 + tw * PXT + q];
    const float* wc = wgt + ((size_t)k0 * 64 + c) * 9;
#pragma unroll
    for (int k = 0; k < KB; ++k) {
      const float* wk = wc + (size_t)k * 64 * 9;
#pragma unroll
      for (int r = 0; r < 3; ++r)
#pragma unroll
        for (int s = 0; s < 3; ++s) {
          float wv = wk[r * 3 + s];
#pragma unroll
          for (int p = 0; p < PXT; ++p) acc[k][p] += wv * in[r][s + p];
        }
    }
    __syncthreads();
  }
#pragma unroll
  for (int k = 0; k < KB; ++k) {
    float bv = bias[k0 + k];
    float4 v = make_float4(acc[k][0] + bv, acc[k][1] + bv, acc[k][2] + bv, acc[k][3] + bv);
    float* op = out + ((((size_t)n * 64 + (k0 + k)) * 224 + (h0 + th)) * 224 + (w0 + tw * PXT));
    *reinterpret_cast<float4*>(op) = v;
  }
}

extern "C" void kernel_launch(void* const* d_in, const int* in_sizes, int n_in,
                              void* d_out, int out_size, void* d_ws, size_t ws_size,
                              hipStream_t stream) {
  const float* x = (const float*)d_in[0];
  const float* W = (const float*)d_in[1];
  const float* b = (const float*)d_in[2];
  float* out = (float*)d_out;

  if (ws_size >= 9 * 64 * 64 * sizeof(unsigned short)) {
    unsigned short* wt = (unsigned short*)d_ws;
    build_wt<<<144, 256, 0, stream>>>(W, wt);
    dim3 grid(7, 14, 16);  // w-tiles, h-tiles, images
    conv3x3_mfma<<<grid, 256, 0, stream>>>(x, wt, b, out);
  } else {
    dim3 grid(7 * 7, 64 / KB, 16);
    conv3x3_direct<<<grid, 256, 0, stream>>>(x, W, b, out);
  }
}